// Round 1
// baseline (198.332 us; speedup 1.0000x reference)
//
#include <hip/hip_runtime.h>
#include <hip/hip_bf16.h>

typedef __bf16 bf16x8 __attribute__((ext_vector_type(8)));
typedef short short8 __attribute__((ext_vector_type(8)));
typedef float f32x4 __attribute__((ext_vector_type(4)));
typedef unsigned short ushort_t;

#define T_LEN 32768
#define B_SZ 4
#define NSLOW 2047
#define NSEQ (B_SZ * NSLOW)   // 8188
#define GH 64
#define G3 192
#define NL 4
#define HID 32
#define NCH 256               // fast-path chunks per batch (len 128)
#define L2E 1.44269504088896341f

// staging-buffer (bf16) element offsets, concatenated in input order
#define OFF_X    0
#define OFF_FCW  131072
#define OFF_FCB  131136
#define OFF_WIH  131200
#define OFF_WHH  180352
#define OFF_BIH  229504
#define OFF_BHH  230272
#define OFF_OFW  231040
#define OFF_OFB  235136
#define OFF_FINW 235200
#define OFF_FINB 235232
#define OFF_FOW  235264
#define OFF_FOB  235296
#define CONV_TOTAL 235297
#define CONV_PAD_BYTES 470656   // 16B-aligned end of staging region

static __device__ __forceinline__ float bf2f(ushort_t u) {
    union { unsigned u; float f; } c; c.u = ((unsigned)u) << 16; return c.f;
}
static __device__ __forceinline__ ushort_t f2bf(float f) {
    union { float f; unsigned u; } c; c.f = f;
    unsigned r = (c.u + 0x7FFFu + ((c.u >> 16) & 1u)) >> 16;
    return (ushort_t)r;
}
static __device__ __forceinline__ unsigned pk2bf(float a, float b) {
    float2 f; f.x = a; f.y = b;
    __hip_bfloat162 h = __float22bfloat162_rn(f);   // v_cvt_pk_bf16_f32
    unsigned u;
    __builtin_memcpy(&u, &h, 4);
    return u;
}
static __device__ __forceinline__ f32x4 mfma16(short8 a, short8 b, f32x4 c) {
    return __builtin_amdgcn_mfma_f32_16x16x32_bf16(
        __builtin_bit_cast(bf16x8, a), __builtin_bit_cast(bf16x8, b), c, 0, 0, 0);
}
// LDS layout: short off = ((t*8 + kb)*16 + (seq ^ (kb&7)))*8 + i
static __device__ __forceinline__ int xoff(int t, int kb, int seq) {
    return ((((t << 3) + kb) << 4) + (seq ^ (kb & 7))) << 3;
}
static __device__ __forceinline__ short8 load_frag_scaled(const ushort_t* p, float s) {
    uint4 r = *(const uint4*)p;
    unsigned aa[4] = {r.x, r.y, r.z, r.w};
    short8 o;
#pragma unroll
    for (int i = 0; i < 4; ++i) {
        o[2 * i]     = (short)f2bf(bf2f((ushort_t)(aa[i] & 0xffffu)) * s);
        o[2 * i + 1] = (short)f2bf(bf2f((ushort_t)(aa[i] >> 16)) * s);
    }
    return o;
}

// ---------------- K0: stage all inputs as bf16 (self-detecting dtype) ------
struct Ptrs13 { const void* p[13]; };

__global__ __launch_bounds__(256) void convert_kernel(Ptrs13 ptrs,
                                                      int* __restrict__ flag,
                                                      ushort_t* __restrict__ dst)
{
    // per-block dtype detection on the first 256 ushorts of x
    __shared__ int scnt;
    if (threadIdx.x == 0) scnt = 0;
    __syncthreads();
    {
        ushort_t u = ((const ushort_t*)ptrs.p[0])[threadIdx.x];
        int e = (u >> 7) & 0xFF;
        int ok = (e >= 80 && e <= 141) ? 1 : 0;
#pragma unroll
        for (int d = 1; d < 64; d <<= 1) ok += __shfl_xor(ok, d, 64);
        if ((threadIdx.x & 63) == 0) atomicAdd(&scnt, ok);
    }
    __syncthreads();
    const bool isbf = (scnt >= 224);   // bf16 data: ~256/256 sane exponents
    if (blockIdx.x == 0 && threadIdx.x == 0) *flag = isbf ? 1 : 0;

    const int offs[14] = {OFF_X, OFF_FCW, OFF_FCB, OFF_WIH, OFF_WHH, OFF_BIH,
                          OFF_BHH, OFF_OFW, OFF_OFB, OFF_FINW, OFF_FINB,
                          OFF_FOW, OFF_FOB, CONV_TOTAL};
    for (int idx = blockIdx.x * 256 + threadIdx.x; idx < CONV_TOTAL;
         idx += gridDim.x * 256) {
        int s = 0;
#pragma unroll
        for (int j = 1; j < 13; ++j) if (idx >= offs[j]) s = j;
        int k = idx - offs[s];
        ushort_t v = isbf ? ((const ushort_t*)ptrs.p[s])[k]
                          : f2bf(((const float*)ptrs.p[s])[k]);
        dst[idx] = v;
    }
}

// ---------------- K1: fused 4-layer GRU + out-FC + sigmoid ----------------
// Orientation: A=weights (m=gate-col), B=activations (n=seq).
// D[col][seq]: lane holds seq = lane&15, cols = jb + 4*quad + i.
//
// NEW: 2-layer pipelined wavefront. Layers run in pairs (0,1) then (2,3);
// at block-step s the same waves compute layer A at t=s and layer B at
// t=s-2 (lag 2 keeps every producer->consumer handoff separated by >=1
// barrier). In-place slot invariants: A writes slot s; B reads slots
// s-1 (px = h_A(t+1)) and s-3 (its own h(t-1)), writes slot s-2, which
// A never re-reads. One barrier per step; 68 barrier-steps vs 128, and
// two independent dependency chains per step to fill the trans/MFMA pipes.
struct LayerState {
    short8 wR0, wR1, wZ0, wZ1, wN0, wN1;   // Wih frags (pre-scaled)
    short8 uR0, uR1, uZ0, uZ1, uN0, uN1;   // Whh frags (pre-scaled)
    f32x4 bR, bZ, bNX, bNH;                // pre-scaled biases
    f32x4 xR, xZ, xN;                      // xacc(t) carried between steps
    f32x4 hc;                              // running h (this lane's 4 cols)
};

static __device__ __forceinline__ void load_layer(
    LayerState& L, int l, const ushort_t* __restrict__ wih,
    const ushort_t* __restrict__ whh, const ushort_t* __restrict__ bih,
    const ushort_t* __restrict__ bhh, int jb, int m, int kofs, int col0)
{
    const ushort_t* wl = wih + l * G3 * GH;
    const ushort_t* ul = whh + l * G3 * GH;
    L.wR0 = load_frag_scaled(wl + (0 * 64 + jb + m) * 64 + kofs, -L2E);
    L.wR1 = load_frag_scaled(wl + (0 * 64 + jb + m) * 64 + 32 + kofs, -L2E);
    L.wZ0 = load_frag_scaled(wl + (1 * 64 + jb + m) * 64 + kofs, -L2E);
    L.wZ1 = load_frag_scaled(wl + (1 * 64 + jb + m) * 64 + 32 + kofs, -L2E);
    L.wN0 = load_frag_scaled(wl + (2 * 64 + jb + m) * 64 + kofs, 2.f * L2E);
    L.wN1 = load_frag_scaled(wl + (2 * 64 + jb + m) * 64 + 32 + kofs, 2.f * L2E);
    L.uR0 = load_frag_scaled(ul + (0 * 64 + jb + m) * 64 + kofs, -L2E);
    L.uR1 = load_frag_scaled(ul + (0 * 64 + jb + m) * 64 + 32 + kofs, -L2E);
    L.uZ0 = load_frag_scaled(ul + (1 * 64 + jb + m) * 64 + kofs, -L2E);
    L.uZ1 = load_frag_scaled(ul + (1 * 64 + jb + m) * 64 + 32 + kofs, -L2E);
    L.uN0 = load_frag_scaled(ul + (2 * 64 + jb + m) * 64 + kofs, 2.f * L2E);
    L.uN1 = load_frag_scaled(ul + (2 * 64 + jb + m) * 64 + 32 + kofs, 2.f * L2E);
#pragma unroll
    for (int i = 0; i < 4; ++i) {
        int c = col0 + i;
        L.bR[i]  = -L2E * (bf2f(bih[l * G3 + c]) + bf2f(bhh[l * G3 + c]));
        L.bZ[i]  = -L2E * (bf2f(bih[l * G3 + 64 + c]) + bf2f(bhh[l * G3 + 64 + c]));
        L.bNX[i] = 2.f * L2E * bf2f(bih[l * G3 + 128 + c]);
        L.bNH[i] = 2.f * L2E * bf2f(bhh[l * G3 + 128 + c]);
    }
    L.hc[0] = L.hc[1] = L.hc[2] = L.hc[3] = 0.f;
}

// One GRU cell (layer L at time t). t is wave-uniform; t<0 / t>31 = no-op.
static __device__ __forceinline__ void gru_step(
    LayerState& L, int t, short8* Xs8, short* Xs, int iA0, int iB0, int wb0)
{
    if (t < 0 || t > 31) return;
    const int iA = iA0 + (t << 7);
    const int iB = iB0 + (t << 7);
    short8 px0, px1;
    if (t < 31) {                       // X(t+1): prefetch early
        px0 = Xs8[iA + 128];
        px1 = Xs8[iB + 128];
    }
    f32x4 aR, aZ, aNH = L.bNH;
    if (t == 0) {
        // peel: h=0, compute xacc(0) in-step from slot 0
        short8 cx0 = Xs8[iA], cx1 = Xs8[iB];
        f32x4 xR = L.bR, xZ = L.bZ, xN = L.bNX;
        xR = mfma16(L.wR0, cx0, xR); xR = mfma16(L.wR1, cx1, xR);
        xZ = mfma16(L.wZ0, cx0, xZ); xZ = mfma16(L.wZ1, cx1, xZ);
        xN = mfma16(L.wN0, cx0, xN); xN = mfma16(L.wN1, cx1, xN);
        L.xR = xR; L.xZ = xZ; L.xN = xN;
        aR = xR; aZ = xZ;
    } else {
        short8 bh0 = Xs8[iA - 128];     // h(t-1), written >=1 barrier ago
        short8 bh1 = Xs8[iB - 128];
        aR  = mfma16(L.uR0, bh0, L.xR); aR  = mfma16(L.uR1, bh1, aR);
        aZ  = mfma16(L.uZ0, bh0, L.xZ); aZ  = mfma16(L.uZ1, bh1, aZ);
        aNH = mfma16(L.uN0, bh0, aNH);  aNH = mfma16(L.uN1, bh1, aNH);
    }
    f32x4 hcv = L.hc;
#pragma unroll
    for (int i = 0; i < 4; ++i) {
        float r = __builtin_amdgcn_rcpf(1.f + __builtin_amdgcn_exp2f(aR[i]));
        float z = __builtin_amdgcn_rcpf(1.f + __builtin_amdgcn_exp2f(aZ[i]));
        float yp = fmaf(r, aNH[i], L.xN[i]);
        float nn = fmaf(-2.f,
            __builtin_amdgcn_rcpf(1.f + __builtin_amdgcn_exp2f(yp)), 1.f);
        hcv[i] = fmaf(z, hcv[i] - nn, nn);
    }
    L.hc = hcv;
    *(uint2*)(Xs + wb0 + (t << 10)) =
        make_uint2(pk2bf(hcv[0], hcv[1]), pk2bf(hcv[2], hcv[3]));
    if (t < 31) {                       // xacc(t+1) in barrier shadow
        f32x4 xR = L.bR, xZ = L.bZ, xN = L.bNX;
        xR = mfma16(L.wR0, px0, xR); xR = mfma16(L.wR1, px1, xR);
        xZ = mfma16(L.wZ0, px0, xZ); xZ = mfma16(L.wZ1, px1, xZ);
        xN = mfma16(L.wN0, px0, xN); xN = mfma16(L.wN1, px1, xN);
        L.xR = xR; L.xZ = xZ; L.xN = xN;
    }
}

__global__ __launch_bounds__(256, 2) void gru_kernel(
    const ushort_t* __restrict__ x, const ushort_t* __restrict__ fcw,
    const ushort_t* __restrict__ fcb, const ushort_t* __restrict__ wih,
    const ushort_t* __restrict__ whh, const ushort_t* __restrict__ bih,
    const ushort_t* __restrict__ bhh, const ushort_t* __restrict__ ofw,
    const ushort_t* __restrict__ ofb, float* __restrict__ Aslow,
    float* __restrict__ gslow)
{
    __shared__ short8 Xs8[4096];   // 64 KB: 16 seq x 32 t x 64 feat, swizzled
    short* Xs = (short*)Xs8;
    const int tid = threadIdx.x;
    const int w = tid >> 6, lane = tid & 63;
    const int q = lane >> 4, m = lane & 15;
    const int jb = w * 16;
    const int n0 = blockIdx.x * 16;

    // ---- fill layer-0 input: relu(x_s * fc_in_w + fc_in_b) ----
#pragma unroll 1
    for (int ii = 0; ii < 16; ++ii) {
        int cid = ii * 256 + tid;
        int seq = cid & 15, kb = (cid >> 4) & 7, t = cid >> 7;
        int n = n0 + seq; if (n > NSEQ - 1) n = NSEQ - 1;
        int b = n / NSLOW, s = n - b * NSLOW;
        float xv = bf2f(x[b * T_LEN + s * 16 + t]);
        short8 v;
#pragma unroll
        for (int i = 0; i < 8; ++i) {
            int g = kb * 8 + i;
            float h = fmaf(xv, bf2f(fcw[g]), bf2f(fcb[g]));
            h = h > 0.f ? h : 0.f;
            v[i] = (short)f2bf(h);
        }
        Xs8[xoff(t, kb, seq) >> 3] = v;
    }

    const int col0 = jb + 4 * q;            // this lane's 4 gate-cols
    const int kbw = (col0 >> 3);            // write feature-block
    const int wsub = (col0 & 7);            // 0 or 4
    const int kofs = q * 8;
    const int wbase0 = ((kbw << 4) + (m ^ (kbw & 7))) * 8 + wsub;
    const int iA0 = xoff(0, q, m) >> 3;     // kb=q chain (+128/t)
    const int iB0 = xoff(0, 4 + q, m) >> 3; // kb=4+q chain

#pragma unroll 1
    for (int p = 0; p < 2; ++p) {
        LayerState LA, LB;
        load_layer(LA, 2 * p,     wih, whh, bih, bhh, jb, m, kofs, col0);
        load_layer(LB, 2 * p + 1, wih, whh, bih, bhh, jb, m, kofs, col0);
#pragma unroll 1
        for (int s = 0; s < 34; ++s) {
            __syncthreads();            // all slots from step s-1 visible
            gru_step(LA, s,     Xs8, Xs, iA0, iB0, wbase0);
            gru_step(LB, s - 2, Xs8, Xs, iA0, iB0, wbase0);
        }
    }

    // ---- epilogue: eps = h_last @ out_fc_w^T + b ----
    __syncthreads();
    short8 aL0 = Xs8[xoff(31, q, m) >> 3];
    short8 aL1 = Xs8[xoff(31, 4 + q, m) >> 3];
    float sc = (w < 2) ? -L2E : 1.f;
    short8 o0 = load_frag_scaled(ofw + (jb + m) * 64 + kofs, sc);
    short8 o1 = load_frag_scaled(ofw + (jb + m) * 64 + 32 + kofs, sc);
    f32x4 aE = {bf2f(ofb[col0]) * sc, bf2f(ofb[col0 + 1]) * sc,
                bf2f(ofb[col0 + 2]) * sc, bf2f(ofb[col0 + 3]) * sc};
    aE = mfma16(o0, aL0, aE);
    aE = mfma16(o1, aL1, aE);
    int n = n0 + m;           // pad rows land in rows < 8192: harmless
    if (w < 2) {
        f32x4 v;
#pragma unroll
        for (int i = 0; i < 4; ++i)
            v[i] = __builtin_amdgcn_rcpf(1.f + __builtin_amdgcn_exp2f(aE[i]));
        *(f32x4*)(Aslow + n * HID + col0) = v;
    } else {
        *(f32x4*)(gslow + n * HID + (col0 - 32)) = aE;
    }
}

// ---------------- K2: per-chunk (prod A, partial sum), 256 chunks ----------
__global__ __launch_bounds__(256) void pass1_kernel(
    const ushort_t* __restrict__ x, const float* __restrict__ Aslow,
    const float* __restrict__ gslow, const ushort_t* __restrict__ finw,
    const ushort_t* __restrict__ finb, float* __restrict__ P,
    float* __restrict__ S)
{
    int gt = blockIdx.x * 256 + threadIdx.x;    // 32768 = 4b * 256c * 32h
    int h = gt & 31, c = (gt >> 5) & 255, b = gt >> 13;
    float fw = bf2f(finw[h]), fb = bf2f(finb[h]);
    float Pv = 1.f, Sv = 0.f;
    int t0 = c * 128;
#pragma unroll 1
    for (int seg = 0; seg < 8; ++seg) {
        int sidx = (t0 >> 4) + seg - 1;
        if (sidx < 0) sidx = 0;
        if (sidx > NSLOW - 1) sidx = NSLOW - 1;
        float A = Aslow[(b * NSLOW + sidx) * HID + h];
        float g = gslow[(b * NSLOW + sidx) * HID + h];
        float fwg = fw * g, fbg = fb * g;
        const uint4* px = (const uint4*)(x + b * T_LEN + t0 + seg * 16);
        uint4 ra = px[0], rb = px[1];
        unsigned xa[8] = {ra.x, ra.y, ra.z, ra.w, rb.x, rb.y, rb.z, rb.w};
#pragma unroll
        for (int j = 0; j < 8; ++j) {
            float x0 = bf2f((ushort_t)(xa[j] & 0xffffu));
            float x1 = bf2f((ushort_t)(xa[j] >> 16));
            Sv = fmaf(A, Sv, fmaf(x0, fwg, fbg));
            Sv = fmaf(A, Sv, fmaf(x1, fwg, fbg));
        }
        float A2 = A * A, A4 = A2 * A2, A8 = A4 * A4;
        Pv *= A8 * A8;
    }
    P[(b * HID + h) * NCH + c] = Pv;
    S[(b * HID + h) * NCH + c] = Sv;
}

// ---------------- K3: scan of chunk summaries ----------------
__global__ __launch_bounds__(128) void scan_kernel(
    const float* __restrict__ P, const float* __restrict__ S,
    float* __restrict__ Hpre)
{
    int tid = threadIdx.x;   // 128 = (b,h)
    const float4* p4 = (const float4*)(P + tid * NCH);
    const float4* s4 = (const float4*)(S + tid * NCH);
    float* hp = Hpre + tid * NCH;
    float hr = 0.f;
#pragma unroll 8
    for (int c = 0; c < NCH / 4; ++c) {
        float4 pv = p4[c], sv = s4[c];
        hp[4 * c + 0] = hr; hr = fmaf(pv.x, hr, sv.x);
        hp[4 * c + 1] = hr; hr = fmaf(pv.y, hr, sv.y);
        hp[4 * c + 2] = hr; hr = fmaf(pv.z, hr, sv.z);
        hp[4 * c + 3] = hr; hr = fmaf(pv.w, hr, sv.w);
    }
}

// ---------------- K4: recompute states + fused output dot ----------------
__global__ __launch_bounds__(256) void pass2_kernel(
    const ushort_t* __restrict__ x, const float* __restrict__ Aslow,
    const float* __restrict__ gslow, const float* __restrict__ Hpre,
    const ushort_t* __restrict__ finw, const ushort_t* __restrict__ finb,
    const ushort_t* __restrict__ fow, const ushort_t* __restrict__ fob,
    const int* __restrict__ flag, void* __restrict__ outv)
{
    int wv = blockIdx.x * 4 + (threadIdx.x >> 6);   // 0..511
    int lane = threadIdx.x & 63;
    int half = lane >> 5, h = lane & 31;
    int pair = wv * 2 + half;                       // 0..1023 = b*NCH + c
    int b = pair >> 8, c = pair & 255;
    const bool isbf = (*flag != 0);
    ushort_t* outb = (ushort_t*)outv;
    float* outf = (float*)outv;
    float hv = Hpre[(b * HID + h) * NCH + c];
    float fw = bf2f(finw[h]), fb = bf2f(finb[h]);
    float wo = bf2f(fow[h]), ob = bf2f(fob[0]);
    int t0 = c * 128;
#pragma unroll 1
    for (int blk = 0; blk < 4; ++blk) {
        float ykeep = 0.f;
        float A = 0.f, fwg = 0.f, fbg = 0.f;
#pragma unroll
        for (int tt = 0; tt < 32; ++tt) {
            int t = t0 + blk * 32 + tt;
            if ((tt & 15) == 0) {
                int sidx = (t >> 4) - 1;
                if (sidx < 0) sidx = 0;
                A = Aslow[(b * NSLOW + sidx) * HID + h];
                float g = gslow[(b * NSLOW + sidx) * HID + h];
                fwg = fw * g; fbg = fb * g;
            }
            float xv = bf2f(x[b * T_LEN + t]);
            hv = fmaf(A, hv, fmaf(xv, fwg, fbg));
            float y = hv * wo;
            y += __shfl_xor(y, 1, 64);
            y += __shfl_xor(y, 2, 64);
            y += __shfl_xor(y, 4, 64);
            y += __shfl_xor(y, 8, 64);
            y += __shfl_xor(y, 16, 64);
            if (tt == h) ykeep = y + ob;
        }
        int oidx = b * T_LEN + t0 + blk * 32 + h;
        if (isbf) outb[oidx] = f2bf(ykeep);
        else      outf[oidx] = ykeep;
    }
}

extern "C" void kernel_launch(void* const* d_in, const int* in_sizes, int n_in,
                              void* d_out, int out_size, void* d_ws, size_t ws_size,
                              hipStream_t stream)
{
    ushort_t* cv = (ushort_t*)d_ws;
    const ushort_t* x    = cv + OFF_X;
    const ushort_t* fcw  = cv + OFF_FCW;
    const ushort_t* fcb  = cv + OFF_FCB;
    const ushort_t* wih  = cv + OFF_WIH;
    const ushort_t* whh  = cv + OFF_WHH;
    const ushort_t* bih  = cv + OFF_BIH;
    const ushort_t* bhh  = cv + OFF_BHH;
    const ushort_t* ofw  = cv + OFF_OFW;
    const ushort_t* ofb  = cv + OFF_OFB;
    const ushort_t* finw = cv + OFF_FINW;
    const ushort_t* finb = cv + OFF_FINB;
    const ushort_t* fow  = cv + OFF_FOW;
    const ushort_t* fob  = cv + OFF_FOB;

    float* Aslow = (float*)((char*)d_ws + CONV_PAD_BYTES);  // 8192*32 f32
    float* gslow = Aslow + 8192 * 32;
    float* P     = gslow + 8192 * 32;          // 4*32*NCH
    float* S     = P + 4 * 32 * NCH;
    float* Hpre  = S + 4 * 32 * NCH;
    int*   flag  = (int*)(Hpre + 4 * 32 * NCH);

    Ptrs13 ptrs;
    for (int i = 0; i < 13; ++i) ptrs.p[i] = d_in[i];

    convert_kernel<<<dim3(920), dim3(256), 0, stream>>>(ptrs, flag, cv);
    gru_kernel<<<dim3(512), dim3(256), 0, stream>>>(
        x, fcw, fcb, wih, whh, bih, bhh, ofw, ofb, Aslow, gslow);
    pass1_kernel<<<dim3(128), dim3(256), 0, stream>>>(
        x, Aslow, gslow, finw, finb, P, S);
    scan_kernel<<<dim3(1), dim3(128), 0, stream>>>(P, S, Hpre);
    pass2_kernel<<<dim3(128), dim3(256), 0, stream>>>(
        x, Aslow, gslow, Hpre, finw, finb, fow, fob, flag, d_out);
}